// Round 1
// baseline (370.011 us; speedup 1.0000x reference)
//
#include <hip/hip_runtime.h>

// Problem constants (from setup_inputs: B=64, L=512, H=1024)
constexpr int BB = 64;
constexpr int LL = 512;
constexpr int HH = 1024;
constexpr int SPLITK = 4;

struct Ptr3 { const float* p[3]; };

// ---------------------------------------------------------------------------
// Skinny GEMM with split-K, deterministic partials.
// out_part[r][y][m][n] = sum_{k in split y} cat(A0[r],A1[r])[m][k] * W[r][k][n]
// A halves each have row stride 1024 (HH). W is [K][HH] row-major.
// Grid: (16 n-tiles, SPLITK, 3 relations), block 256.
// ---------------------------------------------------------------------------
template<int K0, int K1>
__global__ __launch_bounds__(256)
void gemm_skinny(Ptr3 A0, Ptr3 A1, Ptr3 Wp, float* __restrict__ part)
{
    constexpr int K = K0 + K1;
    constexpr int KRANGE = K / SPLITK;
    __shared__ float As[32][64];   // [kk][m] (transposed for float4 compute reads)
    __shared__ float Ws[32][64];   // [kk][n]
    const int r   = blockIdx.z;
    const int n0  = blockIdx.x * 64;
    const int ks  = blockIdx.y * KRANGE;
    const int tid = threadIdx.x;
    const float* a0 = A0.p[r];
    const float* a1 = A1.p[r];
    const float* w  = Wp.p[r];

    const int tn = tid & 15;   // n quad index
    const int tm = tid >> 4;   // m quad index

    float acc[4][4] = {};

    for (int kt = ks; kt < ks + KRANGE; kt += 32) {
        // Stage A tile: each thread loads 8 consecutive k for one m (coalesced),
        // scatter-writes into transposed LDS.
        {
            const int m   = tid >> 2;          // 0..63
            const int kk0 = (tid & 3) << 3;    // 0,8,16,24
            const int kg  = kt + kk0;
            const float* src = (kg < K0) ? (a0 + m * HH + kg)
                                         : (a1 + m * HH + (kg - K0));
            float4 v0 = *(const float4*)(src);
            float4 v1 = *(const float4*)(src + 4);
            As[kk0 + 0][m] = v0.x; As[kk0 + 1][m] = v0.y;
            As[kk0 + 2][m] = v0.z; As[kk0 + 3][m] = v0.w;
            As[kk0 + 4][m] = v1.x; As[kk0 + 5][m] = v1.y;
            As[kk0 + 6][m] = v1.z; As[kk0 + 7][m] = v1.w;
        }
        // Stage W tile: float4 coalesced, no transpose needed.
        {
            const int j4 = (tid & 15) << 2;
            int kk = tid >> 4;                 // 0..15, then +16
            #pragma unroll
            for (int i = 0; i < 2; i++, kk += 16) {
                *(float4*)&Ws[kk][j4] = *(const float4*)(w + (size_t)(kt + kk) * HH + n0 + j4);
            }
        }
        __syncthreads();
        #pragma unroll
        for (int kk = 0; kk < 32; kk++) {
            float4 a4 = *(const float4*)&As[kk][tm << 2];
            float4 b4 = *(const float4*)&Ws[kk][tn << 2];
            float av[4] = {a4.x, a4.y, a4.z, a4.w};
            float bv[4] = {b4.x, b4.y, b4.z, b4.w};
            #pragma unroll
            for (int i = 0; i < 4; i++)
                #pragma unroll
                for (int j = 0; j < 4; j++)
                    acc[i][j] += av[i] * bv[j];
        }
        __syncthreads();
    }

    float* dst = part + (size_t)((r * SPLITK + blockIdx.y) * 64) * HH + n0 + (tn << 2);
    #pragma unroll
    for (int i = 0; i < 4; i++) {
        const int m = (tm << 2) + i;
        *(float4*)(dst + (size_t)m * HH) = make_float4(acc[i][0], acc[i][1], acc[i][2], acc[i][3]);
    }
}

// ---------------------------------------------------------------------------
// Sum SPLITK partials -> dst[3][64][1024], optional tanh.
// Grid 192 x 256 threads, float4 per thread (3*64*1024 = 196608 floats).
// ---------------------------------------------------------------------------
template<bool TANH>
__global__ __launch_bounds__(256)
void reduce_split(const float* __restrict__ part, float* __restrict__ dst)
{
    const int i4   = blockIdx.x * 256 + threadIdx.x;
    const int flat = i4 << 2;
    const int r    = flat >> 16;        // 65536 floats per relation
    const int mn   = flat & 65535;
    const float* p = part + (size_t)r * SPLITK * 65536 + mn;
    float4 s = *(const float4*)p;
    #pragma unroll
    for (int y = 1; y < SPLITK; y++) {
        float4 q = *(const float4*)(p + (size_t)y * 65536);
        s.x += q.x; s.y += q.y; s.z += q.z; s.w += q.w;
    }
    if (TANH) {
        s.x = tanhf(s.x); s.y = tanhf(s.y); s.z = tanhf(s.z); s.w = tanhf(s.w);
    }
    *(float4*)(dst + (size_t)r * 65536 + mn) = s;
}

// ---------------------------------------------------------------------------
// Attention scores: attn[r][b][l] = dot(enc[b][l][:], t[r][b][:]).
// One wave handles 8 l's; target vectors register-cached (12 float4/lane).
// Grid: 64 b * 16 l-chunks = 1024 blocks, block 256 (4 waves * 8 l = 32 l/blk).
// ---------------------------------------------------------------------------
__global__ __launch_bounds__(256)
void attn_scores(const float* __restrict__ enc, const float* __restrict__ t,
                 float* __restrict__ attn)
{
    const int b    = blockIdx.x >> 4;
    const int lc   = blockIdx.x & 15;
    const int lane = threadIdx.x & 63;
    const int wave = threadIdx.x >> 6;

    float4 tr[3][4];
    #pragma unroll
    for (int r = 0; r < 3; r++)
        #pragma unroll
        for (int v = 0; v < 4; v++)
            tr[r][v] = *(const float4*)&t[(size_t)(r * BB + b) * HH + (lane << 2) + (v << 8)];

    const int lbase = (lc << 5) + (wave << 3);
    for (int i = 0; i < 8; i++) {
        const int l = lbase + i;
        const float* e = enc + (size_t)(b * LL + l) * HH;
        float a0 = 0.f, a1 = 0.f, a2 = 0.f;
        #pragma unroll
        for (int v = 0; v < 4; v++) {
            float4 ev = *(const float4*)&e[(lane << 2) + (v << 8)];
            a0 += ev.x * tr[0][v].x + ev.y * tr[0][v].y + ev.z * tr[0][v].z + ev.w * tr[0][v].w;
            a1 += ev.x * tr[1][v].x + ev.y * tr[1][v].y + ev.z * tr[1][v].z + ev.w * tr[1][v].w;
            a2 += ev.x * tr[2][v].x + ev.y * tr[2][v].y + ev.z * tr[2][v].z + ev.w * tr[2][v].w;
        }
        #pragma unroll
        for (int off = 32; off > 0; off >>= 1) {
            a0 += __shfl_xor(a0, off);
            a1 += __shfl_xor(a1, off);
            a2 += __shfl_xor(a2, off);
        }
        if (lane == 0) {
            attn[(size_t)(0 * BB + b) * LL + l] = a0;
            attn[(size_t)(1 * BB + b) * LL + l] = a1;
            attn[(size_t)(2 * BB + b) * LL + l] = a2;
        }
    }
}

// ---------------------------------------------------------------------------
// Fused softmax (block-level, over L=512, per relation) + weighted context:
// wctx[r][b][h] = sum_l softmax(attn[r][b][:])[l] * enc[b][l][h]
// Grid: (64 b, 4 h-chunks of 256), block 256.
// ---------------------------------------------------------------------------
__global__ __launch_bounds__(256)
void wctx_softmax(const float* __restrict__ enc, const float* __restrict__ attn,
                  float* __restrict__ wctx)
{
    __shared__ float p[3][LL];
    __shared__ float red[256];
    const int b   = blockIdx.x;
    const int hc  = blockIdx.y;
    const int tid = threadIdx.x;

    #pragma unroll
    for (int r = 0; r < 3; r++) {
        float2 v = *(const float2*)&attn[(size_t)(r * BB + b) * LL + tid * 2];
        *(float2*)&p[r][tid * 2] = v;
    }
    __syncthreads();

    #pragma unroll
    for (int r = 0; r < 3; r++) {
        const float v0 = p[r][tid];
        const float v1 = p[r][tid + 256];
        red[tid] = fmaxf(v0, v1);
        __syncthreads();
        for (int s = 128; s > 0; s >>= 1) {
            if (tid < s) red[tid] = fmaxf(red[tid], red[tid + s]);
            __syncthreads();
        }
        const float m = red[0];
        __syncthreads();
        const float e0 = __expf(v0 - m);
        const float e1 = __expf(v1 - m);
        red[tid] = e0 + e1;
        __syncthreads();
        for (int s = 128; s > 0; s >>= 1) {
            if (tid < s) red[tid] += red[tid + s];
            __syncthreads();
        }
        const float inv = 1.0f / red[0];
        __syncthreads();
        p[r][tid]       = e0 * inv;
        p[r][tid + 256] = e1 * inv;
        __syncthreads();
    }

    const int h = (hc << 8) + tid;
    const float* e = enc + (size_t)b * LL * HH + h;
    float a0 = 0.f, a1 = 0.f, a2 = 0.f;
    #pragma unroll 8
    for (int l = 0; l < LL; l++) {
        const float ev = e[(size_t)l * HH];
        a0 += p[0][l] * ev;
        a1 += p[1][l] * ev;
        a2 += p[2][l] * ev;
    }
    wctx[(size_t)(0 * BB + b) * HH + h] = a0;
    wctx[(size_t)(1 * BB + b) * HH + h] = a1;
    wctx[(size_t)(2 * BB + b) * HH + h] = a2;
}

// ---------------------------------------------------------------------------
// Final: sum split partials, tanh, broadcast F copies into out[r][b][f][h].
// F read from device scalar (full_feature_len). Grid 192 x 256, float4/thread.
// ---------------------------------------------------------------------------
__global__ __launch_bounds__(256)
void reduce_tanh_broadcast(const float* __restrict__ part, const int* __restrict__ Fp,
                           float* __restrict__ out)
{
    const int i4   = blockIdx.x * 256 + threadIdx.x;
    const int flat = i4 << 2;
    const int r    = flat >> 16;
    const int mn   = flat & 65535;
    const float* p = part + (size_t)r * SPLITK * 65536 + mn;
    float4 s = *(const float4*)p;
    #pragma unroll
    for (int y = 1; y < SPLITK; y++) {
        float4 q = *(const float4*)(p + (size_t)y * 65536);
        s.x += q.x; s.y += q.y; s.z += q.z; s.w += q.w;
    }
    s.x = tanhf(s.x); s.y = tanhf(s.y); s.z = tanhf(s.z); s.w = tanhf(s.w);

    const int F  = *Fp;
    const int bb = mn >> 10;
    const int hh = mn & 1023;
    float* o = out + ((size_t)(r * BB + bb) * F) * HH + hh;
    for (int f = 0; f < F; f++)
        *(float4*)(o + (size_t)f * HH) = s;
}

// ---------------------------------------------------------------------------
extern "C" void kernel_launch(void* const* d_in, const int* in_sizes, int n_in,
                              void* d_out, int out_size, void* d_ws, size_t ws_size,
                              hipStream_t stream)
{
    (void)in_sizes; (void)n_in; (void)out_size; (void)ws_size;
    const float* hs  = (const float*)d_in[0];   // h_tilde_s [B,H]
    const float* ho  = (const float*)d_in[1];   // h_tilde_o
    const float* ha  = (const float*)d_in[2];   // h_tilde_a
    const float* enc = (const float*)d_in[3];   // enc_out [B,L,H]
    const int*   Fp  = (const int*)d_in[4];     // full_feature_len
    const float* W_as    = (const float*)d_in[5];
    const float* W_so    = (const float*)d_in[6];
    const float* W_oa    = (const float*)d_in[7];
    const float* Win_as  = (const float*)d_in[8];
    const float* Win_so  = (const float*)d_in[9];
    const float* Win_oa  = (const float*)d_in[10];
    const float* Wout_as = (const float*)d_in[11];
    const float* Wout_so = (const float*)d_in[12];
    const float* Wout_oa = (const float*)d_in[13];

    float* ws   = (float*)d_ws;
    float* part = ws;              // [3][SPLITK][64][1024] = 786432 floats
    float* hx   = ws + 786432;     // [3][64][1024]
    float* tt   = ws + 983040;     // [3][64][1024]
    float* at   = ws + 1179648;    // [3][64][512]
    float* wc   = ws + 1277952;    // [3][64][1024]

    // Stage 1: h_x = tanh(cat(.,.) @ W_x)   (as: [a|s], so: [s|o], oa: [o|a])
    {
        Ptr3 A0{{ha, hs, ho}};
        Ptr3 A1{{hs, ho, ha}};
        Ptr3 W {{W_as, W_so, W_oa}};
        gemm_skinny<1024, 1024><<<dim3(16, SPLITK, 3), 256, 0, stream>>>(A0, A1, W, part);
    }
    reduce_split<true><<<192, 256, 0, stream>>>(part, hx);

    // Stage 2: t_x = h_x @ Win_x
    {
        Ptr3 A0{{hx, hx + 65536, hx + 131072}};
        Ptr3 A1{{nullptr, nullptr, nullptr}};
        Ptr3 W {{Win_as, Win_so, Win_oa}};
        gemm_skinny<1024, 0><<<dim3(16, SPLITK, 3), 256, 0, stream>>>(A0, A1, W, part);
    }
    reduce_split<false><<<192, 256, 0, stream>>>(part, tt);

    // Stage 3: scores
    attn_scores<<<1024, 256, 0, stream>>>(enc, tt, at);

    // Stage 4: softmax + weighted context
    wctx_softmax<<<dim3(64, 4), 256, 0, stream>>>(enc, at, wc);

    // Stage 5: sa_x = tanh(cat(wctx_x, h_x) @ Wout_x)
    {
        Ptr3 A0{{wc, wc + 65536, wc + 131072}};
        Ptr3 A1{{hx, hx + 65536, hx + 131072}};
        Ptr3 W {{Wout_as, Wout_so, Wout_oa}};
        gemm_skinny<1024, 1024><<<dim3(16, SPLITK, 3), 256, 0, stream>>>(A0, A1, W, part);
    }

    // Stage 6: reduce + tanh + broadcast to [3][B][F][H]
    reduce_tanh_broadcast<<<192, 256, 0, stream>>>(part, Fp, (float*)d_out);
}

// Round 2
// 346.894 us; speedup vs baseline: 1.0666x; 1.0666x over previous
//
#include <hip/hip_runtime.h>

// Problem constants (from setup_inputs: B=64, L=512, H=1024)
constexpr int BB = 64;
constexpr int LL = 512;
constexpr int HH = 1024;
constexpr int SPLITS = 16;               // split-K factor for all GEMMs
constexpr int RSTRIDE = 3 * BB * HH;     // 196608: stride between wc partial bufs

struct Ptr3 { const float* p[3]; };

// ---------------------------------------------------------------------------
// Skinny GEMM, split-K=16, deterministic partials.
// part[(r*16+y)*64+m][n] = sum_{k in split y} cat(A0[r],A1[r])[m][k] * W[r][k][n]
// NSUM0: number of partial buffers (stride RSTRIDE) to sum when loading A0
// (used by stage 5 to consume the 4 l-split wctx partials for free).
// Grid: (16 n-tiles, 16 splits, 3 relations), block 256 -> 768 blocks, 3/CU.
// ---------------------------------------------------------------------------
template<int K0, int K1, int NSUM0>
__global__ __launch_bounds__(256)
void gemm_skinny(Ptr3 A0, Ptr3 A1, Ptr3 Wp, float* __restrict__ part)
{
    constexpr int K = K0 + K1;
    constexpr int KRANGE = K / SPLITS;
    __shared__ float As[32][64];   // [kk][m]
    __shared__ float Ws[32][64];   // [kk][n]
    const int r   = blockIdx.z;
    const int n0  = blockIdx.x * 64;
    const int ks  = blockIdx.y * KRANGE;
    const int tid = threadIdx.x;
    const float* a0 = A0.p[r];
    const float* a1 = A1.p[r];
    const float* w  = Wp.p[r];

    const int tn = tid & 15;   // n quad index
    const int tm = tid >> 4;   // m quad index

    float acc[4][4] = {};

    for (int kt = ks; kt < ks + KRANGE; kt += 32) {
        // Stage A tile: thread loads 8 consecutive k for one m (coalesced),
        // scatter-writes transposed into LDS. Optionally sums NSUM0 partials.
        {
            const int m   = tid >> 2;          // 0..63
            const int kk0 = (tid & 3) << 3;    // 0,8,16,24
            const int kg  = kt + kk0;
            float4 v0, v1;
            if (K1 == 0 || kg < K0) {
                const float* src = a0 + (size_t)m * HH + kg;
                v0 = *(const float4*)(src);
                v1 = *(const float4*)(src + 4);
                #pragma unroll
                for (int j = 1; j < NSUM0; j++) {
                    float4 q0 = *(const float4*)(src + (size_t)j * RSTRIDE);
                    float4 q1 = *(const float4*)(src + (size_t)j * RSTRIDE + 4);
                    v0.x += q0.x; v0.y += q0.y; v0.z += q0.z; v0.w += q0.w;
                    v1.x += q1.x; v1.y += q1.y; v1.z += q1.z; v1.w += q1.w;
                }
            } else {
                const float* src = a1 + (size_t)m * HH + (kg - K0);
                v0 = *(const float4*)(src);
                v1 = *(const float4*)(src + 4);
            }
            As[kk0 + 0][m] = v0.x; As[kk0 + 1][m] = v0.y;
            As[kk0 + 2][m] = v0.z; As[kk0 + 3][m] = v0.w;
            As[kk0 + 4][m] = v1.x; As[kk0 + 5][m] = v1.y;
            As[kk0 + 6][m] = v1.z; As[kk0 + 7][m] = v1.w;
        }
        // Stage W tile: float4 coalesced, row-major, no transpose.
        {
            const int j4 = (tid & 15) << 2;
            int kk = tid >> 4;                 // 0..15, then +16
            #pragma unroll
            for (int i = 0; i < 2; i++, kk += 16) {
                *(float4*)&Ws[kk][j4] = *(const float4*)(w + (size_t)(kt + kk) * HH + n0 + j4);
            }
        }
        __syncthreads();
        #pragma unroll
        for (int kk = 0; kk < 32; kk++) {
            float4 a4 = *(const float4*)&As[kk][tm << 2];
            float4 b4 = *(const float4*)&Ws[kk][tn << 2];
            float av[4] = {a4.x, a4.y, a4.z, a4.w};
            float bv[4] = {b4.x, b4.y, b4.z, b4.w};
            #pragma unroll
            for (int i = 0; i < 4; i++)
                #pragma unroll
                for (int j = 0; j < 4; j++)
                    acc[i][j] += av[i] * bv[j];
        }
        __syncthreads();
    }

    float* dst = part + (size_t)((r * SPLITS + blockIdx.y) * 64) * HH + n0 + (tn << 2);
    #pragma unroll
    for (int i = 0; i < 4; i++) {
        const int m = (tm << 2) + i;
        *(float4*)(dst + (size_t)m * HH) = make_float4(acc[i][0], acc[i][1], acc[i][2], acc[i][3]);
    }
}

// ---------------------------------------------------------------------------
// Sum SPLITS partials -> dst[3][64][1024], + tanh. Grid 192 x 256, float4/th.
// ---------------------------------------------------------------------------
__global__ __launch_bounds__(256)
void reduce_tanh(const float* __restrict__ part, float* __restrict__ dst)
{
    const int i4   = blockIdx.x * 256 + threadIdx.x;
    const int flat = i4 << 2;
    const int r    = flat >> 16;        // 65536 floats per relation
    const int mn   = flat & 65535;
    const float* p = part + (size_t)r * SPLITS * 65536 + mn;
    float4 s = *(const float4*)p;
    #pragma unroll
    for (int y = 1; y < SPLITS; y++) {
        float4 q = *(const float4*)(p + (size_t)y * 65536);
        s.x += q.x; s.y += q.y; s.z += q.z; s.w += q.w;
    }
    s.x = tanhf(s.x); s.y = tanhf(s.y); s.z = tanhf(s.z); s.w = tanhf(s.w);
    *(float4*)(dst + (size_t)r * 65536 + mn) = s;
}

// ---------------------------------------------------------------------------
// Attention scores: attn[r][b][l] = dot(enc[b][l][:], t[r][b][:]) where the
// target t is consumed directly from stage-2 split partials (summed here).
// Grid: 64 b * 16 l-chunks = 1024 blocks, block 256 (4 waves * 8 l = 32 l).
// ---------------------------------------------------------------------------
__global__ __launch_bounds__(256)
void attn_scores(const float* __restrict__ enc, const float* __restrict__ part,
                 float* __restrict__ attn)
{
    const int b    = blockIdx.x >> 4;
    const int lc   = blockIdx.x & 15;
    const int lane = threadIdx.x & 63;
    const int wave = threadIdx.x >> 6;

    // Register-cache the 3 target vectors (sum 16 split partials on the fly).
    float4 tr[3][4];
    #pragma unroll
    for (int r = 0; r < 3; r++) {
        #pragma unroll
        for (int v = 0; v < 4; v++) tr[r][v] = make_float4(0.f, 0.f, 0.f, 0.f);
        #pragma unroll
        for (int y = 0; y < SPLITS; y++) {
            const float* q = part + ((size_t)((r * SPLITS + y) * 64 + b)) * HH + (lane << 2);
            #pragma unroll
            for (int v = 0; v < 4; v++) {
                float4 t4 = *(const float4*)(q + (v << 8));
                tr[r][v].x += t4.x; tr[r][v].y += t4.y;
                tr[r][v].z += t4.z; tr[r][v].w += t4.w;
            }
        }
    }

    const int lbase = (lc << 5) + (wave << 3);
    for (int i = 0; i < 8; i++) {
        const int l = lbase + i;
        const float* e = enc + (size_t)(b * LL + l) * HH;
        float a0 = 0.f, a1 = 0.f, a2 = 0.f;
        #pragma unroll
        for (int v = 0; v < 4; v++) {
            float4 ev = *(const float4*)&e[(lane << 2) + (v << 8)];
            a0 += ev.x * tr[0][v].x + ev.y * tr[0][v].y + ev.z * tr[0][v].z + ev.w * tr[0][v].w;
            a1 += ev.x * tr[1][v].x + ev.y * tr[1][v].y + ev.z * tr[1][v].z + ev.w * tr[1][v].w;
            a2 += ev.x * tr[2][v].x + ev.y * tr[2][v].y + ev.z * tr[2][v].z + ev.w * tr[2][v].w;
        }
        #pragma unroll
        for (int off = 32; off > 0; off >>= 1) {
            a0 += __shfl_xor(a0, off);
            a1 += __shfl_xor(a1, off);
            a2 += __shfl_xor(a2, off);
        }
        if (lane == 0) {
            attn[(size_t)(0 * BB + b) * LL + l] = a0;
            attn[(size_t)(1 * BB + b) * LL + l] = a1;
            attn[(size_t)(2 * BB + b) * LL + l] = a2;
        }
    }
}

// ---------------------------------------------------------------------------
// Row softmax over L=512: one wave per (r,b) row. Grid 192 x 64.
// ---------------------------------------------------------------------------
__global__ __launch_bounds__(64)
void softmax_rows(const float* __restrict__ at, float* __restrict__ pn)
{
    const int row  = blockIdx.x;        // r*64 + b
    const int lane = threadIdx.x;
    const float* src = at + (size_t)row * LL + lane * 8;
    float4 x0 = *(const float4*)src;
    float4 x1 = *(const float4*)(src + 4);
    float m = fmaxf(fmaxf(fmaxf(x0.x, x0.y), fmaxf(x0.z, x0.w)),
                    fmaxf(fmaxf(x1.x, x1.y), fmaxf(x1.z, x1.w)));
    #pragma unroll
    for (int off = 32; off > 0; off >>= 1) m = fmaxf(m, __shfl_xor(m, off));
    float4 e0, e1;
    e0.x = __expf(x0.x - m); e0.y = __expf(x0.y - m);
    e0.z = __expf(x0.z - m); e0.w = __expf(x0.w - m);
    e1.x = __expf(x1.x - m); e1.y = __expf(x1.y - m);
    e1.z = __expf(x1.z - m); e1.w = __expf(x1.w - m);
    float s = e0.x + e0.y + e0.z + e0.w + e1.x + e1.y + e1.z + e1.w;
    #pragma unroll
    for (int off = 32; off > 0; off >>= 1) s += __shfl_xor(s, off);
    const float inv = 1.0f / s;
    e0.x *= inv; e0.y *= inv; e0.z *= inv; e0.w *= inv;
    e1.x *= inv; e1.y *= inv; e1.z *= inv; e1.w *= inv;
    float* dst = pn + (size_t)row * LL + lane * 8;
    *(float4*)dst = e0;
    *(float4*)(dst + 4) = e1;
}

// ---------------------------------------------------------------------------
// Weighted context, l-split partials:
// wcp[ls][r][b][h] = sum_{l in split ls} pn[r][b][l] * enc[b][l][h]
// Grid: (64 b, 4 hc, 4 ls) = 1024 blocks, block 256 (4 waves x 32 l each).
// ---------------------------------------------------------------------------
__global__ __launch_bounds__(256)
void wctx_partial(const float* __restrict__ enc, const float* __restrict__ pn,
                  float* __restrict__ wcp)
{
    __shared__ float pl[3][128];
    __shared__ float4 red[3][3][64];   // waves 1..3 stash their partial accs
    const int b    = blockIdx.x;
    const int hc   = blockIdx.y;
    const int ls   = blockIdx.z;
    const int tid  = threadIdx.x;
    const int lane = tid & 63;
    const int lg   = tid >> 6;

    #pragma unroll
    for (int r = 0; r < 3; r++)
        if (tid < 128) pl[r][tid] = pn[(size_t)(r * BB + b) * LL + ls * 128 + tid];
    __syncthreads();

    const int h = (hc << 8) + (lane << 2);
    const float* e = enc + ((size_t)b * LL + ls * 128 + lg * 32) * HH + h;
    float4 a0 = make_float4(0.f, 0.f, 0.f, 0.f);
    float4 a1 = a0, a2 = a0;
    #pragma unroll 8
    for (int i = 0; i < 32; i++) {
        float4 ev = *(const float4*)(e + (size_t)i * HH);
        const float q0 = pl[0][lg * 32 + i];
        const float q1 = pl[1][lg * 32 + i];
        const float q2 = pl[2][lg * 32 + i];
        a0.x += ev.x * q0; a0.y += ev.y * q0; a0.z += ev.z * q0; a0.w += ev.w * q0;
        a1.x += ev.x * q1; a1.y += ev.y * q1; a1.z += ev.z * q1; a1.w += ev.w * q1;
        a2.x += ev.x * q2; a2.y += ev.y * q2; a2.z += ev.z * q2; a2.w += ev.w * q2;
    }

    if (lg > 0) {
        red[lg - 1][0][lane] = a0;
        red[lg - 1][1][lane] = a1;
        red[lg - 1][2][lane] = a2;
    }
    __syncthreads();
    if (lg == 0) {
        #pragma unroll
        for (int w = 0; w < 3; w++) {
            float4 q;
            q = red[w][0][lane];
            a0.x += q.x; a0.y += q.y; a0.z += q.z; a0.w += q.w;
            q = red[w][1][lane];
            a1.x += q.x; a1.y += q.y; a1.z += q.z; a1.w += q.w;
            q = red[w][2][lane];
            a2.x += q.x; a2.y += q.y; a2.z += q.z; a2.w += q.w;
        }
        float* dst = wcp + (size_t)ls * RSTRIDE + (size_t)b * HH + h;
        *(float4*)(dst + 0 * BB * HH) = a0;
        *(float4*)(dst + 1 * BB * HH) = a1;
        *(float4*)(dst + 2 * BB * HH) = a2;
    }
}

// ---------------------------------------------------------------------------
// Final: sum split partials, tanh, broadcast F copies into out[r][b][f][h].
// ---------------------------------------------------------------------------
__global__ __launch_bounds__(256)
void reduce_tanh_broadcast(const float* __restrict__ part, const int* __restrict__ Fp,
                           float* __restrict__ out)
{
    const int i4   = blockIdx.x * 256 + threadIdx.x;
    const int flat = i4 << 2;
    const int r    = flat >> 16;
    const int mn   = flat & 65535;
    const float* p = part + (size_t)r * SPLITS * 65536 + mn;
    float4 s = *(const float4*)p;
    #pragma unroll
    for (int y = 1; y < SPLITS; y++) {
        float4 q = *(const float4*)(p + (size_t)y * 65536);
        s.x += q.x; s.y += q.y; s.z += q.z; s.w += q.w;
    }
    s.x = tanhf(s.x); s.y = tanhf(s.y); s.z = tanhf(s.z); s.w = tanhf(s.w);

    const int F  = *Fp;
    const int bb = mn >> 10;
    const int hh = mn & 1023;
    float* o = out + ((size_t)(r * BB + bb) * F) * HH + hh;
    for (int f = 0; f < F; f++)
        *(float4*)(o + (size_t)f * HH) = s;
}

// ---------------------------------------------------------------------------
extern "C" void kernel_launch(void* const* d_in, const int* in_sizes, int n_in,
                              void* d_out, int out_size, void* d_ws, size_t ws_size,
                              hipStream_t stream)
{
    (void)in_sizes; (void)n_in; (void)out_size; (void)ws_size;
    const float* hs  = (const float*)d_in[0];
    const float* ho  = (const float*)d_in[1];
    const float* ha  = (const float*)d_in[2];
    const float* enc = (const float*)d_in[3];
    const int*   Fp  = (const int*)d_in[4];
    const float* W_as    = (const float*)d_in[5];
    const float* W_so    = (const float*)d_in[6];
    const float* W_oa    = (const float*)d_in[7];
    const float* Win_as  = (const float*)d_in[8];
    const float* Win_so  = (const float*)d_in[9];
    const float* Win_oa  = (const float*)d_in[10];
    const float* Wout_as = (const float*)d_in[11];
    const float* Wout_so = (const float*)d_in[12];
    const float* Wout_oa = (const float*)d_in[13];

    float* ws   = (float*)d_ws;
    float* part = ws;                   // [3][16][64][1024] = 3145728 floats
    float* hx   = ws + 3145728;         // [3][64][1024]
    float* at   = ws + 3342336;         // [3][64][512]
    float* pn   = ws + 3440640;         // [3][64][512]
    float* wcp  = ws + 3538944;         // [4][3][64][1024]

    // Stage 1: h_x = tanh(cat(.,.) @ W_x)   (as: [a|s], so: [s|o], oa: [o|a])
    {
        Ptr3 A0{{ha, hs, ho}};
        Ptr3 A1{{hs, ho, ha}};
        Ptr3 W {{W_as, W_so, W_oa}};
        gemm_skinny<1024, 1024, 1><<<dim3(16, SPLITS, 3), 256, 0, stream>>>(A0, A1, W, part);
    }
    reduce_tanh<<<192, 256, 0, stream>>>(part, hx);

    // Stage 2: t_x = h_x @ Win_x  (partials consumed directly by attn_scores)
    {
        Ptr3 A0{{hx, hx + 65536, hx + 131072}};
        Ptr3 A1{{nullptr, nullptr, nullptr}};
        Ptr3 W {{Win_as, Win_so, Win_oa}};
        gemm_skinny<1024, 0, 1><<<dim3(16, SPLITS, 3), 256, 0, stream>>>(A0, A1, W, part);
    }

    // Stage 3: scores (sums stage-2 partials inline)
    attn_scores<<<1024, 256, 0, stream>>>(enc, part, at);

    // Stage 4a: softmax rows
    softmax_rows<<<192, 64, 0, stream>>>(at, pn);

    // Stage 4b: weighted context, 4 l-split partials
    wctx_partial<<<dim3(64, 4, 4), 256, 0, stream>>>(enc, pn, wcp);

    // Stage 5: sa_x = tanh(cat(wctx_x, h_x) @ Wout_x); A0 sums the 4 partials
    {
        Ptr3 A0{{wcp, wcp + 65536, wcp + 131072}};
        Ptr3 A1{{hx, hx + 65536, hx + 131072}};
        Ptr3 W {{Wout_as, Wout_so, Wout_oa}};
        gemm_skinny<1024, 1024, 4><<<dim3(16, SPLITS, 3), 256, 0, stream>>>(A0, A1, W, part);
    }

    // Stage 6: reduce + tanh + broadcast to [3][B][F][H]
    reduce_tanh_broadcast<<<192, 256, 0, stream>>>(part, Fp, (float*)d_out);
}

// Round 3
// 323.386 us; speedup vs baseline: 1.1442x; 1.0727x over previous
//
#include <hip/hip_runtime.h>

// Problem constants (from setup_inputs: B=64, L=512, H=1024)
constexpr int BB = 64;
constexpr int LL = 512;
constexpr int HH = 1024;
constexpr int SPLITS = 16;               // split-K factor for all GEMMs

struct Ptr3 { const float* p[3]; };

// ---------------------------------------------------------------------------
// Skinny GEMM, split-K=16, deterministic partials.
// part[(r*16+y)*64+m][n] = sum_{k in split y} cat(A0[r],A1[r])[m][k] * W[r][k][n]
// Grid: (16 n-tiles, 16 splits, 3 relations) = 768 blocks, 256 thr (3/CU).
// ---------------------------------------------------------------------------
template<int K0, int K1>
__global__ __launch_bounds__(256)
void gemm_skinny(Ptr3 A0, Ptr3 A1, Ptr3 Wp, float* __restrict__ part)
{
    constexpr int K = K0 + K1;
    constexpr int KRANGE = K / SPLITS;
    __shared__ float As[32][64];   // [kk][m]
    __shared__ float Ws[32][64];   // [kk][n]
    const int r   = blockIdx.z;
    const int n0  = blockIdx.x * 64;
    const int ks  = blockIdx.y * KRANGE;
    const int tid = threadIdx.x;
    const float* a0 = A0.p[r];
    const float* a1 = A1.p[r];
    const float* w  = Wp.p[r];

    const int tn = tid & 15;   // n quad index
    const int tm = tid >> 4;   // m quad index

    float acc[4][4] = {};

    for (int kt = ks; kt < ks + KRANGE; kt += 32) {
        {
            const int m   = tid >> 2;          // 0..63
            const int kk0 = (tid & 3) << 3;    // 0,8,16,24
            const int kg  = kt + kk0;
            const float* src = (K1 == 0 || kg < K0) ? (a0 + (size_t)m * HH + kg)
                                                    : (a1 + (size_t)m * HH + (kg - K0));
            float4 v0 = *(const float4*)(src);
            float4 v1 = *(const float4*)(src + 4);
            As[kk0 + 0][m] = v0.x; As[kk0 + 1][m] = v0.y;
            As[kk0 + 2][m] = v0.z; As[kk0 + 3][m] = v0.w;
            As[kk0 + 4][m] = v1.x; As[kk0 + 5][m] = v1.y;
            As[kk0 + 6][m] = v1.z; As[kk0 + 7][m] = v1.w;
        }
        {
            const int j4 = (tid & 15) << 2;
            int kk = tid >> 4;
            #pragma unroll
            for (int i = 0; i < 2; i++, kk += 16) {
                *(float4*)&Ws[kk][j4] = *(const float4*)(w + (size_t)(kt + kk) * HH + n0 + j4);
            }
        }
        __syncthreads();
        #pragma unroll
        for (int kk = 0; kk < 32; kk++) {
            float4 a4 = *(const float4*)&As[kk][tm << 2];
            float4 b4 = *(const float4*)&Ws[kk][tn << 2];
            float av[4] = {a4.x, a4.y, a4.z, a4.w};
            float bv[4] = {b4.x, b4.y, b4.z, b4.w};
            #pragma unroll
            for (int i = 0; i < 4; i++)
                #pragma unroll
                for (int j = 0; j < 4; j++)
                    acc[i][j] += av[i] * bv[j];
        }
        __syncthreads();
    }

    float* dst = part + (size_t)((r * SPLITS + blockIdx.y) * 64) * HH + n0 + (tn << 2);
    #pragma unroll
    for (int i = 0; i < 4; i++) {
        const int m = (tm << 2) + i;
        *(float4*)(dst + (size_t)m * HH) = make_float4(acc[i][0], acc[i][1], acc[i][2], acc[i][3]);
    }
}

// ---------------------------------------------------------------------------
// Sum SPLITS partials -> dst[3][64][1024], optional tanh. Grid 192 x 256.
// ---------------------------------------------------------------------------
template<bool TANH>
__global__ __launch_bounds__(256)
void reduce_split(const float* __restrict__ part, float* __restrict__ dst)
{
    const int i4   = blockIdx.x * 256 + threadIdx.x;
    const int flat = i4 << 2;
    const int r    = flat >> 16;
    const int mn   = flat & 65535;
    const float* p = part + (size_t)r * SPLITS * 65536 + mn;
    float4 s = *(const float4*)p;
    #pragma unroll
    for (int y = 1; y < SPLITS; y++) {
        float4 q = *(const float4*)(p + (size_t)y * 65536);
        s.x += q.x; s.y += q.y; s.z += q.z; s.w += q.w;
    }
    if (TANH) {
        s.x = tanhf(s.x); s.y = tanhf(s.y); s.z = tanhf(s.z); s.w = tanhf(s.w);
    }
    *(float4*)(dst + (size_t)r * 65536 + mn) = s;
}

// ---------------------------------------------------------------------------
// Flash attention chunk kernel: block owns (b, chunk of 16 l-rows).
// Each wave holds 4 enc rows in registers, computes 3 scores per row
// (butterfly shuffle), wave-local unnormalized softmax, accumulates
// o = sum_l exp(s_l - m)*enc[l]. Waves merge via LDS; block emits
// opm[chunk][r][1024] and ms[chunk][r] = (M, S). enc read ONCE from HBM.
// Grid: 64 b * 32 chunks = 2048 blocks, 256 threads.
// ---------------------------------------------------------------------------
__global__ __launch_bounds__(256)
void flash_chunk(const float* __restrict__ enc, const float* __restrict__ tt,
                 float* __restrict__ opm, float* __restrict__ ms)
{
    __shared__ float o_l[4][3][HH];    // 48 KB
    __shared__ float ms_sh[4][3][2];
    const int b    = blockIdx.x >> 5;
    const int lc   = blockIdx.x & 31;
    const int tid  = threadIdx.x;
    const int lane = tid & 63;
    const int w    = tid >> 6;

    // Target vectors in registers: tr[r][v] covers h = lane*4 + v*256.
    float4 tr[3][4];
    #pragma unroll
    for (int r = 0; r < 3; r++)
        #pragma unroll
        for (int v = 0; v < 4; v++)
            tr[r][v] = *(const float4*)&tt[(size_t)(r * BB + b) * HH + (lane << 2) + (v << 8)];

    // Load this wave's 4 enc rows into registers.
    const int l0 = (lc << 4) + (w << 2);
    const float* e = enc + ((size_t)b * LL + l0) * HH + (lane << 2);
    float4 ev[4][4];
    #pragma unroll
    for (int j = 0; j < 4; j++)
        #pragma unroll
        for (int v = 0; v < 4; v++)
            ev[j][v] = *(const float4*)(e + (size_t)j * HH + (v << 8));

    // Scores: s[r][j] = dot(enc[l0+j], t_r), broadcast to all lanes.
    float s[3][4];
    #pragma unroll
    for (int j = 0; j < 4; j++) {
        float d0 = 0.f, d1 = 0.f, d2 = 0.f;
        #pragma unroll
        for (int v = 0; v < 4; v++) {
            const float4 x = ev[j][v];
            d0 += x.x * tr[0][v].x + x.y * tr[0][v].y + x.z * tr[0][v].z + x.w * tr[0][v].w;
            d1 += x.x * tr[1][v].x + x.y * tr[1][v].y + x.z * tr[1][v].z + x.w * tr[1][v].w;
            d2 += x.x * tr[2][v].x + x.y * tr[2][v].y + x.z * tr[2][v].z + x.w * tr[2][v].w;
        }
        #pragma unroll
        for (int off = 32; off > 0; off >>= 1) {
            d0 += __shfl_xor(d0, off);
            d1 += __shfl_xor(d1, off);
            d2 += __shfl_xor(d2, off);
        }
        s[0][j] = d0; s[1][j] = d1; s[2][j] = d2;
    }

    // Wave-local softmax (unnormalized) + o accumulation; stash to LDS.
    #pragma unroll
    for (int r = 0; r < 3; r++) {
        const float m = fmaxf(fmaxf(s[r][0], s[r][1]), fmaxf(s[r][2], s[r][3]));
        float p[4];
        float sum = 0.f;
        #pragma unroll
        for (int j = 0; j < 4; j++) { p[j] = __expf(s[r][j] - m); sum += p[j]; }
        #pragma unroll
        for (int v = 0; v < 4; v++) {
            float4 o = make_float4(0.f, 0.f, 0.f, 0.f);
            #pragma unroll
            for (int j = 0; j < 4; j++) {
                const float4 x = ev[j][v];
                o.x += p[j] * x.x; o.y += p[j] * x.y;
                o.z += p[j] * x.z; o.w += p[j] * x.w;
            }
            *(float4*)&o_l[w][r][(lane << 2) + (v << 8)] = o;
        }
        if (lane == 0) { ms_sh[w][r][0] = m; ms_sh[w][r][1] = sum; }
    }
    __syncthreads();

    // Cross-wave merge: thread owns h = tid*4.
    const int chunk = (b << 5) + lc;
    #pragma unroll
    for (int r = 0; r < 3; r++) {
        float m0 = ms_sh[0][r][0], m1 = ms_sh[1][r][0];
        float m2 = ms_sh[2][r][0], m3 = ms_sh[3][r][0];
        const float M = fmaxf(fmaxf(m0, m1), fmaxf(m2, m3));
        const float w0 = __expf(m0 - M), w1 = __expf(m1 - M);
        const float w2 = __expf(m2 - M), w3 = __expf(m3 - M);
        float4 q0 = *(const float4*)&o_l[0][r][tid << 2];
        float4 q1 = *(const float4*)&o_l[1][r][tid << 2];
        float4 q2 = *(const float4*)&o_l[2][r][tid << 2];
        float4 q3 = *(const float4*)&o_l[3][r][tid << 2];
        float4 acc;
        acc.x = w0 * q0.x + w1 * q1.x + w2 * q2.x + w3 * q3.x;
        acc.y = w0 * q0.y + w1 * q1.y + w2 * q2.y + w3 * q3.y;
        acc.z = w0 * q0.z + w1 * q1.z + w2 * q2.z + w3 * q3.z;
        acc.w = w0 * q0.w + w1 * q1.w + w2 * q2.w + w3 * q3.w;
        *(float4*)&opm[((size_t)chunk * 3 + r) * HH + (tid << 2)] = acc;
        if (tid == 0) {
            const float S = w0 * ms_sh[0][r][1] + w1 * ms_sh[1][r][1]
                          + w2 * ms_sh[2][r][1] + w3 * ms_sh[3][r][1];
            ms[((size_t)chunk * 3 + r) * 2 + 0] = M;
            ms[((size_t)chunk * 3 + r) * 2 + 1] = S;
        }
    }
}

// ---------------------------------------------------------------------------
// Combine 32 chunks per (b, r): log-sum-exp merge -> wc[r][b][h].
// Grid: (64 b, 3 r), 256 threads; thread owns h = tid*4.
// ---------------------------------------------------------------------------
__global__ __launch_bounds__(256)
void flash_combine(const float* __restrict__ opm, const float* __restrict__ ms,
                   float* __restrict__ wc)
{
    __shared__ float ms_l[32][2];
    const int b   = blockIdx.x;
    const int r   = blockIdx.y;
    const int tid = threadIdx.x;

    if (tid < 32) {
        const int chunk = (b << 5) + tid;
        ms_l[tid][0] = ms[((size_t)chunk * 3 + r) * 2 + 0];
        ms_l[tid][1] = ms[((size_t)chunk * 3 + r) * 2 + 1];
    }
    __syncthreads();

    float M = -3.4e38f;
    #pragma unroll 8
    for (int c = 0; c < 32; c++) M = fmaxf(M, ms_l[c][0]);

    float S = 0.f;
    float4 acc = make_float4(0.f, 0.f, 0.f, 0.f);
    #pragma unroll 4
    for (int c = 0; c < 32; c++) {
        const float wgt = __expf(ms_l[c][0] - M);
        S += wgt * ms_l[c][1];
        const int chunk = (b << 5) + c;
        float4 q = *(const float4*)&opm[((size_t)chunk * 3 + r) * HH + (tid << 2)];
        acc.x += wgt * q.x; acc.y += wgt * q.y;
        acc.z += wgt * q.z; acc.w += wgt * q.w;
    }
    const float inv = 1.0f / S;
    acc.x *= inv; acc.y *= inv; acc.z *= inv; acc.w *= inv;
    *(float4*)&wc[(size_t)(r * BB + b) * HH + (tid << 2)] = acc;
}

// ---------------------------------------------------------------------------
// Final: sum split partials, tanh, broadcast F copies into out[r][b][f][h].
// ---------------------------------------------------------------------------
__global__ __launch_bounds__(256)
void reduce_tanh_broadcast(const float* __restrict__ part, const int* __restrict__ Fp,
                           float* __restrict__ out)
{
    const int i4   = blockIdx.x * 256 + threadIdx.x;
    const int flat = i4 << 2;
    const int r    = flat >> 16;
    const int mn   = flat & 65535;
    const float* p = part + (size_t)r * SPLITS * 65536 + mn;
    float4 s = *(const float4*)p;
    #pragma unroll
    for (int y = 1; y < SPLITS; y++) {
        float4 q = *(const float4*)(p + (size_t)y * 65536);
        s.x += q.x; s.y += q.y; s.z += q.z; s.w += q.w;
    }
    s.x = tanhf(s.x); s.y = tanhf(s.y); s.z = tanhf(s.z); s.w = tanhf(s.w);

    const int F  = *Fp;
    const int bb = mn >> 10;
    const int hh = mn & 1023;
    float* o = out + ((size_t)(r * BB + bb) * F) * HH + hh;
    for (int f = 0; f < F; f++)
        *(float4*)(o + (size_t)f * HH) = s;
}

// ---------------------------------------------------------------------------
extern "C" void kernel_launch(void* const* d_in, const int* in_sizes, int n_in,
                              void* d_out, int out_size, void* d_ws, size_t ws_size,
                              hipStream_t stream)
{
    (void)in_sizes; (void)n_in; (void)out_size; (void)ws_size;
    const float* hs  = (const float*)d_in[0];
    const float* ho  = (const float*)d_in[1];
    const float* ha  = (const float*)d_in[2];
    const float* enc = (const float*)d_in[3];
    const int*   Fp  = (const int*)d_in[4];
    const float* W_as    = (const float*)d_in[5];
    const float* W_so    = (const float*)d_in[6];
    const float* W_oa    = (const float*)d_in[7];
    const float* Win_as  = (const float*)d_in[8];
    const float* Win_so  = (const float*)d_in[9];
    const float* Win_oa  = (const float*)d_in[10];
    const float* Wout_as = (const float*)d_in[11];
    const float* Wout_so = (const float*)d_in[12];
    const float* Wout_oa = (const float*)d_in[13];

    float* ws   = (float*)d_ws;
    float* part = ws;                   // [3][16][64][1024] = 3,145,728 floats
    float* hx   = ws + 3145728;         // [3][64][1024]
    float* tt   = ws + 3342336;         // [3][64][1024]
    float* wc   = ws + 3538944;         // [3][64][1024]
    float* opm  = ws + 3735552;         // [2048][3][1024] = 6,291,456 floats
    float* msb  = ws + 10027008;        // [2048][3][2]

    // Stage 1: h_x = tanh(cat(.,.) @ W_x)   (as: [a|s], so: [s|o], oa: [o|a])
    {
        Ptr3 A0{{ha, hs, ho}};
        Ptr3 A1{{hs, ho, ha}};
        Ptr3 W {{W_as, W_so, W_oa}};
        gemm_skinny<1024, 1024><<<dim3(16, SPLITS, 3), 256, 0, stream>>>(A0, A1, W, part);
    }
    reduce_split<true><<<192, 256, 0, stream>>>(part, hx);

    // Stage 2: t_x = h_x @ Win_x
    {
        Ptr3 A0{{hx, hx + 65536, hx + 131072}};
        Ptr3 A1{{nullptr, nullptr, nullptr}};
        Ptr3 W {{Win_as, Win_so, Win_oa}};
        gemm_skinny<1024, 0><<<dim3(16, SPLITS, 3), 256, 0, stream>>>(A0, A1, W, part);
    }
    reduce_split<false><<<192, 256, 0, stream>>>(part, tt);

    // Stage 3: fused scores + softmax + weighted context (one enc pass)
    flash_chunk<<<2048, 256, 0, stream>>>(enc, tt, opm, msb);
    flash_combine<<<dim3(64, 3), 256, 0, stream>>>(opm, msb, wc);

    // Stage 5: sa_x = tanh(cat(wctx_x, h_x) @ Wout_x)
    {
        Ptr3 A0{{wc, wc + 65536, wc + 131072}};
        Ptr3 A1{{hx, hx + 65536, hx + 131072}};
        Ptr3 W {{Wout_as, Wout_so, Wout_oa}};
        gemm_skinny<1024, 1024><<<dim3(16, SPLITS, 3), 256, 0, stream>>>(A0, A1, W, part);
    }

    // Stage 6: reduce + tanh + broadcast to [3][B][F][H]
    reduce_tanh_broadcast<<<192, 256, 0, stream>>>(part, Fp, (float*)d_out);
}

// Round 5
// 310.785 us; speedup vs baseline: 1.1906x; 1.0405x over previous
//
#include <hip/hip_runtime.h>

// Problem constants (from setup_inputs: B=64, L=512, H=1024)
constexpr int BB = 64;
constexpr int LL = 512;
constexpr int HH = 1024;
constexpr int SPLITS = 16;               // split-K factor for all GEMMs

typedef float nt_float4 __attribute__((ext_vector_type(4)));

struct Ptr3 { const float* p[3]; };

// ---------------------------------------------------------------------------
// Skinny GEMM, split-K=16, deterministic partials.
// part[(r*16+y)*64+m][n] = sum_{k in split y} cat(A0[r],A1[r])[m][k] * W[r][k][n]
// Grid: (16 n-tiles, 16 splits, 3 relations) = 768 blocks, 256 thr (3/CU).
// ---------------------------------------------------------------------------
template<int K0, int K1>
__global__ __launch_bounds__(256)
void gemm_skinny(Ptr3 A0, Ptr3 A1, Ptr3 Wp, float* __restrict__ part)
{
    constexpr int K = K0 + K1;
    constexpr int KRANGE = K / SPLITS;
    __shared__ float As[32][64];   // [kk][m]
    __shared__ float Ws[32][64];   // [kk][n]
    const int r   = blockIdx.z;
    const int n0  = blockIdx.x * 64;
    const int ks  = blockIdx.y * KRANGE;
    const int tid = threadIdx.x;
    const float* a0 = A0.p[r];
    const float* a1 = A1.p[r];
    const float* w  = Wp.p[r];

    const int tn = tid & 15;   // n quad index
    const int tm = tid >> 4;   // m quad index

    float acc[4][4] = {};

    for (int kt = ks; kt < ks + KRANGE; kt += 32) {
        {
            const int m   = tid >> 2;          // 0..63
            const int kk0 = (tid & 3) << 3;    // 0,8,16,24
            const int kg  = kt + kk0;
            const float* src = (K1 == 0 || kg < K0) ? (a0 + (size_t)m * HH + kg)
                                                    : (a1 + (size_t)m * HH + (kg - K0));
            float4 v0 = *(const float4*)(src);
            float4 v1 = *(const float4*)(src + 4);
            As[kk0 + 0][m] = v0.x; As[kk0 + 1][m] = v0.y;
            As[kk0 + 2][m] = v0.z; As[kk0 + 3][m] = v0.w;
            As[kk0 + 4][m] = v1.x; As[kk0 + 5][m] = v1.y;
            As[kk0 + 6][m] = v1.z; As[kk0 + 7][m] = v1.w;
        }
        {
            const int j4 = (tid & 15) << 2;
            int kk = tid >> 4;
            #pragma unroll
            for (int i = 0; i < 2; i++, kk += 16) {
                *(float4*)&Ws[kk][j4] = *(const float4*)(w + (size_t)(kt + kk) * HH + n0 + j4);
            }
        }
        __syncthreads();
        #pragma unroll
        for (int kk = 0; kk < 32; kk++) {
            float4 a4 = *(const float4*)&As[kk][tm << 2];
            float4 b4 = *(const float4*)&Ws[kk][tn << 2];
            float av[4] = {a4.x, a4.y, a4.z, a4.w};
            float bv[4] = {b4.x, b4.y, b4.z, b4.w};
            #pragma unroll
            for (int i = 0; i < 4; i++)
                #pragma unroll
                for (int j = 0; j < 4; j++)
                    acc[i][j] += av[i] * bv[j];
        }
        __syncthreads();
    }

    float* dst = part + (size_t)((r * SPLITS + blockIdx.y) * 64) * HH + n0 + (tn << 2);
    #pragma unroll
    for (int i = 0; i < 4; i++) {
        const int m = (tm << 2) + i;
        *(float4*)(dst + (size_t)m * HH) = make_float4(acc[i][0], acc[i][1], acc[i][2], acc[i][3]);
    }
}

// ---------------------------------------------------------------------------
// Sum SPLITS partials -> dst[3][64][1024], optional tanh. Grid 192 x 256.
// ---------------------------------------------------------------------------
template<bool TANH>
__global__ __launch_bounds__(256)
void reduce_split(const float* __restrict__ part, float* __restrict__ dst)
{
    const int i4   = blockIdx.x * 256 + threadIdx.x;
    const int flat = i4 << 2;
    const int r    = flat >> 16;
    const int mn   = flat & 65535;
    const float* p = part + (size_t)r * SPLITS * 65536 + mn;
    float4 s = *(const float4*)p;
    #pragma unroll
    for (int y = 1; y < SPLITS; y++) {
        float4 q = *(const float4*)(p + (size_t)y * 65536);
        s.x += q.x; s.y += q.y; s.z += q.z; s.w += q.w;
    }
    if (TANH) {
        s.x = tanhf(s.x); s.y = tanhf(s.y); s.z = tanhf(s.z); s.w = tanhf(s.w);
    }
    *(float4*)(dst + (size_t)r * 65536 + mn) = s;
}

// ---------------------------------------------------------------------------
// Flash attention, 64 l-rows per block with online softmax in registers.
// Each wave iterates 4x over 4 enc rows: score via butterfly shuffle, then
// rescale-accumulate (m, S, o). One LDS merge at the end; block emits
// opm[chunk][r][1024] and ms[chunk][r] = (M, S).  enc read ONCE from HBM.
// Grid: 64 b * 8 chunks = 512 blocks (2/CU, fully co-resident), 256 thr.
// ---------------------------------------------------------------------------
__global__ __launch_bounds__(256)
void flash_chunk(const float* __restrict__ enc, const float* __restrict__ tt,
                 float* __restrict__ opm, float* __restrict__ ms)
{
    __shared__ float o_l[4][3][HH];    // 48 KB
    __shared__ float ms_sh[4][3][2];
    const int b    = blockIdx.x >> 3;
    const int lc   = blockIdx.x & 7;
    const int tid  = threadIdx.x;
    const int lane = tid & 63;
    const int w    = tid >> 6;

    // Target vectors in registers: tr[r][v] covers h = lane*4 + v*256.
    float4 tr[3][4];
    #pragma unroll
    for (int r = 0; r < 3; r++)
        #pragma unroll
        for (int v = 0; v < 4; v++)
            tr[r][v] = *(const float4*)&tt[(size_t)(r * BB + b) * HH + (lane << 2) + (v << 8)];

    // Online-softmax state per relation.
    float  m_run[3] = {-3.0e38f, -3.0e38f, -3.0e38f};
    float  S_run[3] = {0.f, 0.f, 0.f};
    float4 o_run[3][4];
    #pragma unroll
    for (int r = 0; r < 3; r++)
        #pragma unroll
        for (int v = 0; v < 4; v++)
            o_run[r][v] = make_float4(0.f, 0.f, 0.f, 0.f);

    const float* ebase = enc + ((size_t)b * LL + (lc << 6) + (w << 2)) * HH + (lane << 2);

    for (int it = 0; it < 4; it++) {
        // Load this wave's 4 enc rows for this iteration.
        const float* e = ebase + (size_t)(it << 4) * HH;
        float4 ev[4][4];
        #pragma unroll
        for (int j = 0; j < 4; j++)
            #pragma unroll
            for (int v = 0; v < 4; v++)
                ev[j][v] = *(const float4*)(e + (size_t)j * HH + (v << 8));

        // Scores s[r][j], broadcast across the wave.
        float s[3][4];
        #pragma unroll
        for (int j = 0; j < 4; j++) {
            float d0 = 0.f, d1 = 0.f, d2 = 0.f;
            #pragma unroll
            for (int v = 0; v < 4; v++) {
                const float4 x = ev[j][v];
                d0 += x.x * tr[0][v].x + x.y * tr[0][v].y + x.z * tr[0][v].z + x.w * tr[0][v].w;
                d1 += x.x * tr[1][v].x + x.y * tr[1][v].y + x.z * tr[1][v].z + x.w * tr[1][v].w;
                d2 += x.x * tr[2][v].x + x.y * tr[2][v].y + x.z * tr[2][v].z + x.w * tr[2][v].w;
            }
            #pragma unroll
            for (int off = 32; off > 0; off >>= 1) {
                d0 += __shfl_xor(d0, off);
                d1 += __shfl_xor(d1, off);
                d2 += __shfl_xor(d2, off);
            }
            s[0][j] = d0; s[1][j] = d1; s[2][j] = d2;
        }

        // Online update per relation.
        #pragma unroll
        for (int r = 0; r < 3; r++) {
            const float mb = fmaxf(fmaxf(s[r][0], s[r][1]), fmaxf(s[r][2], s[r][3]));
            const float mn_ = fmaxf(m_run[r], mb);
            const float alpha = __expf(m_run[r] - mn_);
            m_run[r] = mn_;
            float p[4];
            float psum = 0.f;
            #pragma unroll
            for (int j = 0; j < 4; j++) { p[j] = __expf(s[r][j] - mn_); psum += p[j]; }
            S_run[r] = S_run[r] * alpha + psum;
            #pragma unroll
            for (int v = 0; v < 4; v++) {
                float4 o = o_run[r][v];
                o.x *= alpha; o.y *= alpha; o.z *= alpha; o.w *= alpha;
                #pragma unroll
                for (int j = 0; j < 4; j++) {
                    const float4 x = ev[j][v];
                    o.x += p[j] * x.x; o.y += p[j] * x.y;
                    o.z += p[j] * x.z; o.w += p[j] * x.w;
                }
                o_run[r][v] = o;
            }
        }
    }

    // Stash wave results to LDS.
    #pragma unroll
    for (int r = 0; r < 3; r++) {
        #pragma unroll
        for (int v = 0; v < 4; v++)
            *(float4*)&o_l[w][r][(lane << 2) + (v << 8)] = o_run[r][v];
        if (lane == 0) { ms_sh[w][r][0] = m_run[r]; ms_sh[w][r][1] = S_run[r]; }
    }
    __syncthreads();

    // Cross-wave merge: thread owns h = tid*4.
    const int chunk = (b << 3) + lc;
    #pragma unroll
    for (int r = 0; r < 3; r++) {
        const float m0 = ms_sh[0][r][0], m1 = ms_sh[1][r][0];
        const float m2 = ms_sh[2][r][0], m3 = ms_sh[3][r][0];
        const float M = fmaxf(fmaxf(m0, m1), fmaxf(m2, m3));
        const float w0 = __expf(m0 - M), w1 = __expf(m1 - M);
        const float w2 = __expf(m2 - M), w3 = __expf(m3 - M);
        float4 q0 = *(const float4*)&o_l[0][r][tid << 2];
        float4 q1 = *(const float4*)&o_l[1][r][tid << 2];
        float4 q2 = *(const float4*)&o_l[2][r][tid << 2];
        float4 q3 = *(const float4*)&o_l[3][r][tid << 2];
        float4 acc;
        acc.x = w0 * q0.x + w1 * q1.x + w2 * q2.x + w3 * q3.x;
        acc.y = w0 * q0.y + w1 * q1.y + w2 * q2.y + w3 * q3.y;
        acc.z = w0 * q0.z + w1 * q1.z + w2 * q2.z + w3 * q3.z;
        acc.w = w0 * q0.w + w1 * q1.w + w2 * q2.w + w3 * q3.w;
        *(float4*)&opm[((size_t)chunk * 3 + r) * HH + (tid << 2)] = acc;
        if (tid == 0) {
            const float S = w0 * ms_sh[0][r][1] + w1 * ms_sh[1][r][1]
                          + w2 * ms_sh[2][r][1] + w3 * ms_sh[3][r][1];
            ms[((size_t)chunk * 3 + r) * 2 + 0] = M;
            ms[((size_t)chunk * 3 + r) * 2 + 1] = S;
        }
    }
}

// ---------------------------------------------------------------------------
// Combine 8 chunks per (b, r): log-sum-exp merge -> wc[r][b][h].
// Grid: (64 b, 3 r), 256 threads; thread owns h = tid*4.
// ---------------------------------------------------------------------------
__global__ __launch_bounds__(256)
void flash_combine(const float* __restrict__ opm, const float* __restrict__ ms,
                   float* __restrict__ wc)
{
    __shared__ float ms_l[8][2];
    const int b   = blockIdx.x;
    const int r   = blockIdx.y;
    const int tid = threadIdx.x;

    if (tid < 8) {
        const int chunk = (b << 3) + tid;
        ms_l[tid][0] = ms[((size_t)chunk * 3 + r) * 2 + 0];
        ms_l[tid][1] = ms[((size_t)chunk * 3 + r) * 2 + 1];
    }
    __syncthreads();

    float M = -3.0e38f;
    #pragma unroll
    for (int c = 0; c < 8; c++) M = fmaxf(M, ms_l[c][0]);

    float S = 0.f;
    float4 acc = make_float4(0.f, 0.f, 0.f, 0.f);
    #pragma unroll
    for (int c = 0; c < 8; c++) {
        const float wgt = __expf(ms_l[c][0] - M);
        S += wgt * ms_l[c][1];
        const int chunk = (b << 3) + c;
        float4 q = *(const float4*)&opm[((size_t)chunk * 3 + r) * HH + (tid << 2)];
        acc.x += wgt * q.x; acc.y += wgt * q.y;
        acc.z += wgt * q.z; acc.w += wgt * q.w;
    }
    const float inv = 1.0f / S;
    acc.x *= inv; acc.y *= inv; acc.z *= inv; acc.w *= inv;
    *(float4*)&wc[(size_t)(r * BB + b) * HH + (tid << 2)] = acc;
}

// ---------------------------------------------------------------------------
// Final: sum split partials, tanh, broadcast F copies into out[r][b][f][h].
// Non-temporal stores: out is write-once, keep L2 clean.
// ---------------------------------------------------------------------------
__global__ __launch_bounds__(256)
void reduce_tanh_broadcast(const float* __restrict__ part, const int* __restrict__ Fp,
                           float* __restrict__ out)
{
    const int i4   = blockIdx.x * 256 + threadIdx.x;
    const int flat = i4 << 2;
    const int r    = flat >> 16;
    const int mn   = flat & 65535;
    const float* p = part + (size_t)r * SPLITS * 65536 + mn;
    float4 s = *(const float4*)p;
    #pragma unroll
    for (int y = 1; y < SPLITS; y++) {
        float4 q = *(const float4*)(p + (size_t)y * 65536);
        s.x += q.x; s.y += q.y; s.z += q.z; s.w += q.w;
    }
    s.x = tanhf(s.x); s.y = tanhf(s.y); s.z = tanhf(s.z); s.w = tanhf(s.w);

    nt_float4 sv;
    sv.x = s.x; sv.y = s.y; sv.z = s.z; sv.w = s.w;

    const int F  = *Fp;
    const int bb = mn >> 10;
    const int hh = mn & 1023;
    float* o = out + ((size_t)(r * BB + bb) * F) * HH + hh;
    for (int f = 0; f < F; f++)
        __builtin_nontemporal_store(sv, (nt_float4*)(o + (size_t)f * HH));
}

// ---------------------------------------------------------------------------
extern "C" void kernel_launch(void* const* d_in, const int* in_sizes, int n_in,
                              void* d_out, int out_size, void* d_ws, size_t ws_size,
                              hipStream_t stream)
{
    (void)in_sizes; (void)n_in; (void)out_size; (void)ws_size;
    const float* hs  = (const float*)d_in[0];
    const float* ho  = (const float*)d_in[1];
    const float* ha  = (const float*)d_in[2];
    const float* enc = (const float*)d_in[3];
    const int*   Fp  = (const int*)d_in[4];
    const float* W_as    = (const float*)d_in[5];
    const float* W_so    = (const float*)d_in[6];
    const float* W_oa    = (const float*)d_in[7];
    const float* Win_as  = (const float*)d_in[8];
    const float* Win_so  = (const float*)d_in[9];
    const float* Win_oa  = (const float*)d_in[10];
    const float* Wout_as = (const float*)d_in[11];
    const float* Wout_so = (const float*)d_in[12];
    const float* Wout_oa = (const float*)d_in[13];

    float* ws   = (float*)d_ws;
    float* part = ws;                   // [3][16][64][1024] = 3,145,728 floats
    float* hx   = ws + 3145728;         // [3][64][1024]
    float* tt   = ws + 3342336;         // [3][64][1024]
    float* wc   = ws + 3538944;         // [3][64][1024]
    float* opm  = ws + 3735552;         // [512][3][1024] = 1,572,864 floats
    float* msb  = ws + 5308416;         // [512][3][2]

    // Stage 1: h_x = tanh(cat(.,.) @ W_x)   (as: [a|s], so: [s|o], oa: [o|a])
    {
        Ptr3 A0{{ha, hs, ho}};
        Ptr3 A1{{hs, ho, ha}};
        Ptr3 W {{W_as, W_so, W_oa}};
        gemm_skinny<1024, 1024><<<dim3(16, SPLITS, 3), 256, 0, stream>>>(A0, A1, W, part);
    }
    reduce_split<true><<<192, 256, 0, stream>>>(part, hx);

    // Stage 2: t_x = h_x @ Win_x
    {
        Ptr3 A0{{hx, hx + 65536, hx + 131072}};
        Ptr3 A1{{nullptr, nullptr, nullptr}};
        Ptr3 W {{Win_as, Win_so, Win_oa}};
        gemm_skinny<1024, 0><<<dim3(16, SPLITS, 3), 256, 0, stream>>>(A0, A1, W, part);
    }
    reduce_split<false><<<192, 256, 0, stream>>>(part, tt);

    // Stage 3: fused scores + softmax + weighted context (one enc pass)
    flash_chunk<<<512, 256, 0, stream>>>(enc, tt, opm, msb);
    flash_combine<<<dim3(64, 3), 256, 0, stream>>>(opm, msb, wc);

    // Stage 5: sa_x = tanh(cat(wctx_x, h_x) @ Wout_x)
    {
        Ptr3 A0{{wc, wc + 65536, wc + 131072}};
        Ptr3 A1{{hx, hx + 65536, hx + 131072}};
        Ptr3 W {{Wout_as, Wout_so, Wout_oa}};
        gemm_skinny<1024, 1024><<<dim3(16, SPLITS, 3), 256, 0, stream>>>(A0, A1, W, part);
    }

    // Stage 6: reduce + tanh + broadcast to [3][B][F][H]
    reduce_tanh_broadcast<<<192, 256, 0, stream>>>(part, Fp, (float*)d_out);
}